// Round 1
// baseline (396.716 us; speedup 1.0000x reference)
//
#include <hip/hip_runtime.h>
#include <cstdint>
#include <cstddef>

// Problem constants
constexpr int B = 64, S = 2048, H = 512, E = 256, V = 32000;
// attention chunking: 32 chunks of 64 keys per batch, 4 waves/block -> 8 blocks/batch
constexpr int NCHUNK = 32;

// ---------------------------------------------------------------------------
// Kernel 1: fused scores + online-softmax partials.
// One wave handles one (b, chunk of 64 keys). lane covers 8 of the 512 dims
// (two float4 slices: d = 4*lane.., d = 256+4*lane..). enc is read ONCE.
// ---------------------------------------------------------------------------
__global__ __launch_bounds__(256) void attn_part_kernel(
    const float* __restrict__ hd, const float* __restrict__ enc,
    float* __restrict__ m_part, float* __restrict__ l_part,
    float* __restrict__ acc_part)
{
    int b = blockIdx.x >> 3;
    int wave = threadIdx.x >> 6, lane = threadIdx.x & 63;
    int chunk = ((blockIdx.x & 7) << 2) + wave;
    int s0 = chunk * 64;

    const float4* hv = (const float4*)(hd + (size_t)b * H);
    float4 h0 = hv[lane], h1 = hv[64 + lane];
    const float4* ev = (const float4*)(enc + (size_t)b * S * H) + (size_t)s0 * (H / 4);

    // first key of the chunk initializes the online-softmax state
    float4 e0 = ev[lane], e1 = ev[64 + lane];
    float p = e0.x * h0.x + e0.y * h0.y + e0.z * h0.z + e0.w * h0.w
            + e1.x * h1.x + e1.y * h1.y + e1.z * h1.z + e1.w * h1.w;
#pragma unroll
    for (int off = 32; off; off >>= 1) p += __shfl_xor(p, off, 64);
    float m = p, l = 1.f;
    float4 a0 = e0, a1 = e1;

    for (int s = 1; s < 64; ++s) {
        const float4* row = ev + (size_t)s * (H / 4);
        e0 = row[lane]; e1 = row[64 + lane];
        p = e0.x * h0.x + e0.y * h0.y + e0.z * h0.z + e0.w * h0.w
          + e1.x * h1.x + e1.y * h1.y + e1.z * h1.z + e1.w * h1.w;
#pragma unroll
        for (int off = 32; off; off >>= 1) p += __shfl_xor(p, off, 64);
        if (p <= m) {                   // common case: max unchanged (wave-uniform branch)
            float w = __expf(p - m);
            l += w;
            a0.x += w * e0.x; a0.y += w * e0.y; a0.z += w * e0.z; a0.w += w * e0.w;
            a1.x += w * e1.x; a1.y += w * e1.y; a1.z += w * e1.z; a1.w += w * e1.w;
        } else {
            float sc = __expf(m - p);
            m = p;
            l = l * sc + 1.f;
            a0.x = a0.x * sc + e0.x; a0.y = a0.y * sc + e0.y;
            a0.z = a0.z * sc + e0.z; a0.w = a0.w * sc + e0.w;
            a1.x = a1.x * sc + e1.x; a1.y = a1.y * sc + e1.y;
            a1.z = a1.z * sc + e1.z; a1.w = a1.w * sc + e1.w;
        }
    }

    int base = b * NCHUNK + chunk;
    if (lane == 0) { m_part[base] = m; l_part[base] = l; }
    float4* ap = (float4*)(acc_part + (size_t)base * H);
    ap[lane] = a0; ap[64 + lane] = a1;
}

// ---------------------------------------------------------------------------
// Kernel 2: combine partials -> ctx; embedding gather; build transposed LSTM
// input inp_t[k][b], k in [0,1280): [0,256)=xe, [256,768)=ctx, [768,1280)=h0.
// ---------------------------------------------------------------------------
__global__ __launch_bounds__(256) void combine_kernel(
    const float* __restrict__ m_part, const float* __restrict__ l_part,
    const float* __restrict__ acc_part, const int* __restrict__ x,
    const float* __restrict__ emb, const float* __restrict__ h0,
    float* __restrict__ inp_t)
{
    int b = blockIdx.x, t = threadIdx.x;
    float M = -1e30f;
    for (int i = 0; i < NCHUNK; ++i) M = fmaxf(M, m_part[b * NCHUNK + i]);
    float L = 0.f;
    for (int i = 0; i < NCHUNK; ++i)
        L += l_part[b * NCHUNK + i] * __expf(m_part[b * NCHUNK + i] - M);
    float invL = 1.f / L;

    for (int d = t; d < H; d += 256) {
        float s = 0.f;
        for (int i = 0; i < NCHUNK; ++i)
            s += __expf(m_part[b * NCHUNK + i] - M) *
                 acc_part[((size_t)(b * NCHUNK + i)) * H + d];
        inp_t[(E + d) * B + b] = s * invL;
    }
    // embedding (E = 256 = blockDim)
    inp_t[t * B + b] = emb[(size_t)x[b] * E + t];
    // previous hidden state, transposed
    for (int d = t; d < H; d += 256)
        inp_t[(E + H + d) * B + b] = h0[b * H + d];
}

// ---------------------------------------------------------------------------
// Kernel 3: one LSTM layer. Block = one output unit j; 4 waves split K;
// lane = batch. Weight-row loads are wave-uniform -> scalar loads (read once).
// Layers 2-4 have zero h/c inputs: w_hh contributes exactly 0 -> skipped.
// ---------------------------------------------------------------------------
__global__ __launch_bounds__(256) void lstm_kernel(
    const float* __restrict__ in_t, int K1,
    const float* __restrict__ w1, const float* __restrict__ w2,
    const float* __restrict__ b_ih, const float* __restrict__ b_hh,
    const float* __restrict__ c0,
    float* __restrict__ h_t_out, float* __restrict__ out_h, float* __restrict__ out_c)
{
    __shared__ float red[4 * 4 * 64 + 4 * 64];
    int j = blockIdx.x;
    int wave = threadIdx.x >> 6, lane = threadIdx.x & 63;
    float acc[4] = {0.f, 0.f, 0.f, 0.f};

    int q1 = K1 >> 2;
    for (int k = wave * q1; k < (wave + 1) * q1; ++k) {
        float xv = in_t[k * B + lane];
#pragma unroll
        for (int g = 0; g < 4; ++g)
            acc[g] += w1[((size_t)(j + 512 * g)) * K1 + k] * xv;
    }
    if (w2) {   // layer 1 only: recurrent part, K2 = 512, input at in_t[K1 + k]
        const int q2 = H >> 2;
        for (int k = wave * q2; k < (wave + 1) * q2; ++k) {
            float xv = in_t[(K1 + k) * B + lane];
#pragma unroll
            for (int g = 0; g < 4; ++g)
                acc[g] += w2[((size_t)(j + 512 * g)) * H + k] * xv;
        }
    }
#pragma unroll
    for (int g = 0; g < 4; ++g) red[(g * 4 + wave) * 64 + lane] = acc[g];
    __syncthreads();
    {
        int g = threadIdx.x >> 6, ln = threadIdx.x & 63;
        float s = red[(g * 4 + 0) * 64 + ln] + red[(g * 4 + 1) * 64 + ln]
                + red[(g * 4 + 2) * 64 + ln] + red[(g * 4 + 3) * 64 + ln];
        red[1024 + g * 64 + ln] = s;
    }
    __syncthreads();
    if (threadIdx.x < 64) {
        int bb = threadIdx.x;
        float gi = red[1024 + 0 * 64 + bb] + b_ih[j]        + b_hh[j];
        float gf = red[1024 + 1 * 64 + bb] + b_ih[j + 512]  + b_hh[j + 512];
        float gg = red[1024 + 2 * 64 + bb] + b_ih[j + 1024] + b_hh[j + 1024];
        float go = red[1024 + 3 * 64 + bb] + b_ih[j + 1536] + b_hh[j + 1536];
        float iv = 1.f / (1.f + expf(-gi));
        float fv = 1.f / (1.f + expf(-gf));
        float gv = tanhf(gg);
        float ov = 1.f / (1.f + expf(-go));
        float cprev = c0 ? c0[bb * H + j] : 0.f;
        float c2 = fv * cprev + iv * gv;
        float hv = ov * tanhf(c2);
        h_t_out[j * B + bb] = hv;                  // transposed for next consumer
        if (out_h) { out_h[bb * H + j] = hv; out_c[bb * H + j] = c2; }
    }
}

// ---------------------------------------------------------------------------
// Kernel 4: logits = z @ fc_w^T + fc_b. z (128 KB) cached in LDS; 16 waves per
// block, each wave owns 8 consecutive vocab rows, lane = batch. fc_w rows are
// wave-uniform -> scalar loads (streamed once, coalesced). LDS transpose before
// store so global writes are 32B-contiguous in v.
// ---------------------------------------------------------------------------
__global__ __launch_bounds__(1024) void fc_kernel(
    const float* __restrict__ z_t, const float* __restrict__ fc_w,
    const float* __restrict__ fc_b, float* __restrict__ out)
{
    __shared__ float zs[H * B];   // 32768 floats = 128 KB
    for (int idx = threadIdx.x; idx < H * B; idx += 1024) zs[idx] = z_t[idx];
    __syncthreads();

    int wave = threadIdx.x >> 6, lane = threadIdx.x & 63;
    int v0 = (blockIdx.x * 16 + wave) * 8;

    float acc[8];
#pragma unroll
    for (int i = 0; i < 8; ++i) acc[i] = fc_b[v0 + i];

#pragma unroll 4
    for (int k = 0; k < H; ++k) {
        float xv = zs[k * B + lane];
#pragma unroll
        for (int i = 0; i < 8; ++i)
            acc[i] += fc_w[((size_t)(v0 + i)) * H + k] * xv;
    }

    __syncthreads();                       // z no longer needed; reuse as transpose buf
#pragma unroll
    for (int i = 0; i < 8; ++i) zs[wave * 512 + lane * 8 + i] = acc[i];
    __syncthreads();
#pragma unroll
    for (int bi = 0; bi < 8; ++bi) {
        int bb = bi * 8 + (lane >> 3);
        out[(size_t)bb * V + v0 + (lane & 7)] = zs[wave * 512 + bi * 64 + lane];
    }
}

// ---------------------------------------------------------------------------
extern "C" void kernel_launch(void* const* d_in, const int* in_sizes, int n_in,
                              void* d_out, int out_size, void* d_ws, size_t ws_size,
                              hipStream_t stream)
{
    const int*   x     = (const int*)d_in[0];
    const float* hdec  = (const float*)d_in[1];
    const float* enc   = (const float*)d_in[2];
    const float* h0    = (const float*)d_in[3];
    const float* c0    = (const float*)d_in[4];
    const float* emb   = (const float*)d_in[5];
    const float* w_ih1 = (const float*)d_in[6];
    const float* w_hh1 = (const float*)d_in[7];
    const float* b_ih1 = (const float*)d_in[8];
    const float* b_hh1 = (const float*)d_in[9];
    const float* w_ih  = (const float*)d_in[10];
    // d_in[11] = w_hh: multiplied by zero hidden state in layers 2-4 -> exactly 0, skipped
    const float* b_ih  = (const float*)d_in[12];
    const float* b_hh  = (const float*)d_in[13];
    const float* fc_w  = (const float*)d_in[14];
    const float* fc_b  = (const float*)d_in[15];

    float* out = (float*)d_out;
    float* ws  = (float*)d_ws;

    // ws layout (floats)
    float* m_part   = ws;                              // 2048
    float* l_part   = ws + 2048;                       // 2048
    float* acc_part = ws + 4096;                       // 64*32*512 = 1048576
    float* inp_t    = acc_part + (size_t)B * NCHUNK * H; // 1280*64 = 81920
    float* zA       = inp_t + 1280 * B;                // 512*64
    float* zB       = zA + H * B;                      // 512*64
    // total ~4.8 MB

    float* out_h = out + (size_t)B * V;          // (1,B,H)
    float* out_c = out_h + (size_t)B * H;        // (1,B,H)

    attn_part_kernel<<<512, 256, 0, stream>>>(hdec, enc, m_part, l_part, acc_part);
    combine_kernel<<<64, 256, 0, stream>>>(m_part, l_part, acc_part, x, emb, h0, inp_t);

    // layer 1: K1=768 (xe+ctx) + recurrent 512 (h0), real c0
    lstm_kernel<<<512, 256, 0, stream>>>(inp_t, 768, w_ih1, w_hh1, b_ih1, b_hh1,
                                         c0, zA, nullptr, nullptr);
    // layers 2-4: zero h/c -> only w_ih matters
    lstm_kernel<<<512, 256, 0, stream>>>(zA, 512, w_ih + 0 * (size_t)2048 * H, nullptr,
                                         b_ih + 0 * 2048, b_hh + 0 * 2048,
                                         nullptr, zB, nullptr, nullptr);
    lstm_kernel<<<512, 256, 0, stream>>>(zB, 512, w_ih + 1 * (size_t)2048 * H, nullptr,
                                         b_ih + 1 * 2048, b_hh + 1 * 2048,
                                         nullptr, zA, nullptr, nullptr);
    lstm_kernel<<<512, 256, 0, stream>>>(zA, 512, w_ih + 2 * (size_t)2048 * H, nullptr,
                                         b_ih + 2 * 2048, b_hh + 2 * 2048,
                                         nullptr, zB, out_h, out_c);

    fc_kernel<<<250, 1024, 0, stream>>>(zB, fc_w, fc_b, out);
}

// Round 2
// 212.978 us; speedup vs baseline: 1.8627x; 1.8627x over previous
//
#include <hip/hip_runtime.h>
#include <cstdint>
#include <cstddef>

// Problem constants
constexpr int B = 64, S = 2048, H = 512, E = 256, V = 32000;
constexpr int NCHUNK = 32;   // attention: 32 chunks of 64 keys per batch

// ---------------------------------------------------------------------------
// Kernel 1: fused scores + online-softmax partials (enc read exactly once).
// One wave per (b, 64-key chunk); lane covers 8 of 512 dims (2 float4 slices).
// ---------------------------------------------------------------------------
__global__ __launch_bounds__(256) void attn_part_kernel(
    const float* __restrict__ hd, const float* __restrict__ enc,
    float* __restrict__ m_part, float* __restrict__ l_part,
    float* __restrict__ acc_part)
{
    int b = blockIdx.x >> 3;
    int wave = threadIdx.x >> 6, lane = threadIdx.x & 63;
    int chunk = ((blockIdx.x & 7) << 2) + wave;
    int s0 = chunk * 64;

    const float4* hv = (const float4*)(hd + (size_t)b * H);
    float4 h0 = hv[lane], h1 = hv[64 + lane];
    const float4* ev = (const float4*)(enc + (size_t)b * S * H) + (size_t)s0 * (H / 4);

    float4 e0 = ev[lane], e1 = ev[64 + lane];
    float p = e0.x * h0.x + e0.y * h0.y + e0.z * h0.z + e0.w * h0.w
            + e1.x * h1.x + e1.y * h1.y + e1.z * h1.z + e1.w * h1.w;
#pragma unroll
    for (int off = 32; off; off >>= 1) p += __shfl_xor(p, off, 64);
    float m = p, l = 1.f;
    float4 a0 = e0, a1 = e1;

    for (int s = 1; s < 64; ++s) {
        const float4* row = ev + (size_t)s * (H / 4);
        e0 = row[lane]; e1 = row[64 + lane];
        p = e0.x * h0.x + e0.y * h0.y + e0.z * h0.z + e0.w * h0.w
          + e1.x * h1.x + e1.y * h1.y + e1.z * h1.z + e1.w * h1.w;
#pragma unroll
        for (int off = 32; off; off >>= 1) p += __shfl_xor(p, off, 64);
        if (p <= m) {
            float w = __expf(p - m);
            l += w;
            a0.x += w * e0.x; a0.y += w * e0.y; a0.z += w * e0.z; a0.w += w * e0.w;
            a1.x += w * e1.x; a1.y += w * e1.y; a1.z += w * e1.z; a1.w += w * e1.w;
        } else {
            float sc = __expf(m - p);
            m = p;
            l = l * sc + 1.f;
            a0.x = a0.x * sc + e0.x; a0.y = a0.y * sc + e0.y;
            a0.z = a0.z * sc + e0.z; a0.w = a0.w * sc + e0.w;
            a1.x = a1.x * sc + e1.x; a1.y = a1.y * sc + e1.y;
            a1.z = a1.z * sc + e1.z; a1.w = a1.w * sc + e1.w;
        }
    }

    int base = b * NCHUNK + chunk;
    if (lane == 0) { m_part[base] = m; l_part[base] = l; }
    float4* ap = (float4*)(acc_part + (size_t)base * H);
    ap[lane] = a0; ap[64 + lane] = a1;
}

// ---------------------------------------------------------------------------
// Kernel 2: combine partials -> ctx; embedding gather; build transposed LSTM
// input inp_t[k][b], k in [0,1280): [0,256)=xe, [256,768)=ctx, [768,1280)=h0.
// ---------------------------------------------------------------------------
__global__ __launch_bounds__(256) void combine_kernel(
    const float* __restrict__ m_part, const float* __restrict__ l_part,
    const float* __restrict__ acc_part, const int* __restrict__ x,
    const float* __restrict__ emb, const float* __restrict__ h0,
    float* __restrict__ inp_t)
{
    int b = blockIdx.x, t = threadIdx.x;
    float M = -1e30f;
    for (int i = 0; i < NCHUNK; ++i) M = fmaxf(M, m_part[b * NCHUNK + i]);
    float L = 0.f;
    for (int i = 0; i < NCHUNK; ++i)
        L += l_part[b * NCHUNK + i] * __expf(m_part[b * NCHUNK + i] - M);
    float invL = 1.f / L;

    for (int d = t; d < H; d += 256) {
        float s = 0.f;
        for (int i = 0; i < NCHUNK; ++i)
            s += __expf(m_part[b * NCHUNK + i] - M) *
                 acc_part[((size_t)(b * NCHUNK + i)) * H + d];
        inp_t[(E + d) * B + b] = s * invL;
    }
    inp_t[t * B + b] = emb[(size_t)x[b] * E + t];
    for (int d = t; d < H; d += 256)
        inp_t[(E + H + d) * B + b] = h0[b * H + d];
}

// ---------------------------------------------------------------------------
// Tiled fp32 GEMM: C[M][64] = A[M][K] (row-major) * X[K][64].
// 512 threads; tile BM x 64, BK=32. A staged TRANSPOSED in LDS ([BK][BM+4]) so
// per-k fragment reads are ds_read_b128; X staged [BK][64], float2 per lane.
// All global weight traffic is coalesced float4 vector loads.
// Supports a 2-matrix concatenated-K input (LSTM layer 1: w_ih1 | w_hh1).
// WMODE 0: write split-K partial P[ck][M][64].
// WMODE 1: write final transposed C[b][ldc] with bias (fc logits).
// ---------------------------------------------------------------------------
template<int BM, int TM, int WMODE>
__global__ __launch_bounds__(512) void gemm_kernel(
    const float* __restrict__ A1, int lda1, int nck1,
    const float* __restrict__ A2, int lda2,
    const float* __restrict__ X,
    float* __restrict__ outp,
    const float* __restrict__ bias,
    int m_tiles, int M, int KC, int ldc)
{
    __shared__ float As[32][BM + 4];
    __shared__ float Xs[32][64];

    int mt = blockIdx.x % m_tiles;
    int ck = blockIdx.x / m_tiles;
    int t = threadIdx.x;
    int tx = t & 31, ty = t >> 5;

    const float* A; int lda; int kA0;
    if (ck < nck1) { A = A1; lda = lda1; kA0 = ck * KC; }
    else           { A = A2; lda = lda2; kA0 = ck * KC - nck1 * KC; }
    int kX0 = ck * KC;
    int m_base = mt * BM;

    float acc[TM][2];
#pragma unroll
    for (int i = 0; i < TM; ++i) { acc[i][0] = 0.f; acc[i][1] = 0.f; }

    for (int k0 = 0; k0 < KC; k0 += 32) {
        {   // stage X tile: 32x64 floats, one float4 per thread
            int k = t >> 4, bq = t & 15;
            float4 v = *(const float4*)&X[(size_t)(kX0 + k0 + k) * 64 + bq * 4];
            *(float4*)&Xs[k][bq * 4] = v;
        }
        {   // stage A tile transposed: BM rows x 32 k
            int kq = t & 7, r = t >> 3;   // r in 0..63
#pragma unroll
            for (int rr = 0; rr < BM / 64; ++rr) {
                int row = r + rr * 64;
                float4 v = *(const float4*)&A[(size_t)(m_base + row) * lda + kA0 + k0 + kq * 4];
                As[kq * 4 + 0][row] = v.x;
                As[kq * 4 + 1][row] = v.y;
                As[kq * 4 + 2][row] = v.z;
                As[kq * 4 + 3][row] = v.w;
            }
        }
        __syncthreads();

#pragma unroll 4
        for (int k = 0; k < 32; ++k) {
            float a[TM];
            *(float4*)&a[0] = *(const float4*)&As[k][ty * TM];
            if constexpr (TM == 8)
                *(float4*)&a[4] = *(const float4*)&As[k][ty * TM + 4];
            float2 xv = *(const float2*)&Xs[k][tx * 2];
#pragma unroll
            for (int i = 0; i < TM; ++i) {
                acc[i][0] += a[i] * xv.x;
                acc[i][1] += a[i] * xv.y;
            }
        }
        __syncthreads();
    }

    if constexpr (WMODE == 0) {
        float* P = outp + (size_t)ck * M * 64;
#pragma unroll
        for (int i = 0; i < TM; ++i) {
            float2 v = make_float2(acc[i][0], acc[i][1]);
            *(float2*)&P[(size_t)(m_base + ty * TM + i) * 64 + tx * 2] = v;
        }
    } else {
#pragma unroll
        for (int j = 0; j < 2; ++j) {
            int b = tx * 2 + j;
#pragma unroll
            for (int i = 0; i < TM; i += 4) {
                int v0 = m_base + ty * TM + i;
                float4 v;
                v.x = acc[i + 0][j] + bias[v0 + 0];
                v.y = acc[i + 1][j] + bias[v0 + 1];
                v.z = acc[i + 2][j] + bias[v0 + 2];
                v.w = acc[i + 3][j] + bias[v0 + 3];
                *(float4*)&outp[(size_t)b * ldc + v0] = v;
            }
        }
    }
}

// ---------------------------------------------------------------------------
// Gate combine + activation: sums split-K partials, adds biases, applies LSTM
// nonlinearity. h written [H][B] (transposed, for next GEMM's X); optional
// [B][H] h/c outputs for the final layer.
// ---------------------------------------------------------------------------
__global__ __launch_bounds__(256) void lstm_act_kernel(
    const float* __restrict__ P, int nck,
    const float* __restrict__ b_ih, const float* __restrict__ b_hh,
    const float* __restrict__ c_prev,
    float* __restrict__ h_t,
    float* __restrict__ out_h, float* __restrict__ out_c)
{
    int idx = blockIdx.x * 256 + threadIdx.x;    // 32768 = H*B
    int b = idx & 63, j = idx >> 6;
    float g[4];
#pragma unroll
    for (int gg = 0; gg < 4; ++gg) {
        int row = j + 512 * gg;
        float s = b_ih[row] + b_hh[row];
        for (int c = 0; c < nck; ++c)
            s += P[((size_t)c * 2048 + row) * 64 + b];
        g[gg] = s;
    }
    float iv = 1.f / (1.f + expf(-g[0]));
    float fv = 1.f / (1.f + expf(-g[1]));
    float gv = tanhf(g[2]);
    float ov = 1.f / (1.f + expf(-g[3]));
    float cp = c_prev ? c_prev[b * H + j] : 0.f;
    float c2 = fv * cp + iv * gv;
    float hv = ov * tanhf(c2);
    h_t[j * B + b] = hv;
    if (out_h) { out_h[b * H + j] = hv; out_c[b * H + j] = c2; }
}

// ---------------------------------------------------------------------------
extern "C" void kernel_launch(void* const* d_in, const int* in_sizes, int n_in,
                              void* d_out, int out_size, void* d_ws, size_t ws_size,
                              hipStream_t stream)
{
    const int*   x     = (const int*)d_in[0];
    const float* hdec  = (const float*)d_in[1];
    const float* enc   = (const float*)d_in[2];
    const float* h0    = (const float*)d_in[3];
    const float* c0    = (const float*)d_in[4];
    const float* emb   = (const float*)d_in[5];
    const float* w_ih1 = (const float*)d_in[6];
    const float* w_hh1 = (const float*)d_in[7];
    const float* b_ih1 = (const float*)d_in[8];
    const float* b_hh1 = (const float*)d_in[9];
    const float* w_ih  = (const float*)d_in[10];
    // d_in[11] = w_hh: multiplied by zero hidden state in layers 2-4 -> skipped
    const float* b_ih  = (const float*)d_in[12];
    const float* b_hh  = (const float*)d_in[13];
    const float* fc_w  = (const float*)d_in[14];
    const float* fc_b  = (const float*)d_in[15];

    float* out = (float*)d_out;
    float* ws  = (float*)d_ws;

    // ws layout (floats), all offsets 16B-aligned
    float* m_part   = ws;                               // 2048
    float* l_part   = ws + 2048;                        // 2048
    float* acc_part = ws + 4096;                        // 64*32*512 = 1048576
    float* inp_t    = acc_part + (size_t)B * NCHUNK * H;// 1280*64 = 81920
    float* zA       = inp_t + 1280 * B;                 // 512*64
    float* zB       = zA + H * B;                       // 512*64
    float* P        = zB + H * B;                       // 10*2048*64 = 1310720

    float* out_h = out + (size_t)B * V;
    float* out_c = out_h + (size_t)B * H;

    // 1) attention (enc read once, 268 MB)
    attn_part_kernel<<<512, 256, 0, stream>>>(hdec, enc, m_part, l_part, acc_part);
    combine_kernel<<<64, 256, 0, stream>>>(m_part, l_part, acc_part, x, emb, h0, inp_t);

    // 2) LSTM layer 1: gates = [w_ih1 | w_hh1] @ inp_t (K = 768+512 = 1280),
    //    split-K KC=128 -> 10 chunks, m_tiles = 2048/64 = 32 -> 320 blocks
    gemm_kernel<64, 4, 0><<<320, 512, 0, stream>>>(
        w_ih1, 768, 6, w_hh1, 512, inp_t, P, nullptr, 32, 2048, 128, 0);
    lstm_act_kernel<<<128, 256, 0, stream>>>(P, 10, b_ih1, b_hh1, c0, zA,
                                             nullptr, nullptr);

    // 3) LSTM layers 2-4 (zero h/c: only w_ih contributes), K=512 -> 4 chunks
    gemm_kernel<64, 4, 0><<<128, 512, 0, stream>>>(
        w_ih + 0 * (size_t)2048 * H, 512, 4, nullptr, 0, zA, P, nullptr, 32, 2048, 128, 0);
    lstm_act_kernel<<<128, 256, 0, stream>>>(P, 4, b_ih + 0 * 2048, b_hh + 0 * 2048,
                                             nullptr, zB, nullptr, nullptr);

    gemm_kernel<64, 4, 0><<<128, 512, 0, stream>>>(
        w_ih + 1 * (size_t)2048 * H, 512, 4, nullptr, 0, zB, P, nullptr, 32, 2048, 128, 0);
    lstm_act_kernel<<<128, 256, 0, stream>>>(P, 4, b_ih + 1 * 2048, b_hh + 1 * 2048,
                                             nullptr, zA, nullptr, nullptr);

    gemm_kernel<64, 4, 0><<<128, 512, 0, stream>>>(
        w_ih + 2 * (size_t)2048 * H, 512, 4, nullptr, 0, zA, P, nullptr, 32, 2048, 128, 0);
    lstm_act_kernel<<<128, 256, 0, stream>>>(P, 4, b_ih + 2 * 2048, b_hh + 2 * 2048,
                                             nullptr, zB, out_h, out_c);

    // 4) logits = zB^T @ fc_w^T + fc_b, written [b][V] directly
    gemm_kernel<128, 8, 1><<<250, 512, 0, stream>>>(
        fc_w, 512, 1, nullptr, 0, zB, out, fc_b, 250, 32000, 512, V);
}